// Round 5
// baseline (157.490 us; speedup 1.0000x reference)
//
#include <hip/hip_runtime.h>
#include <hip/hip_cooperative_groups.h>
#include <math.h>

namespace cg = cooperative_groups;

#define BB 2
#define LL 1024
#define DD 256
#define UU 32
#define RPB 8                   // rows per block
#define UNION (128 + RPB - 1)   // 135-row union band
#define TPB 1024
#define NBLK ((BB * LL) / RPB)  // 256 blocks = 1 per CU (cooperative co-resident)
#define GRP 4                   // phase-3 j-stride groups (waves 0..3)
#define NROW (BB * LL)          // 2048
// prescale so tanh(v) = 1 - 2*rcp(exp2(SC*v)+1), SC = 2*log2(e)
#define SCALE 2.88539008177793f

__global__ __launch_bounds__(TPB, 4) void fused_kernel(
    const float* __restrict__ x, const float* __restrict__ Wt,
    const float* __restrict__ Wx, const float* __restrict__ bh,
    const float* __restrict__ Wa, const float* __restrict__ ba,
    float* __restrict__ out, float* __restrict__ qs, float* __restrict__ kT)
{
    __shared__ float s_a[UNION * 9];        // e-values, [jru][r] pad 9 (144B row = 16B aligned)
    __shared__ float s_part[GRP * RPB * DD];// phase-3 partials (32 KB)
    __shared__ float s_inv[RPB];

    int t = threadIdx.x;
    int blk = blockIdx.x;
    int i0L = (blk * RPB) & (LL - 1);       // local row base
    int b   = (blk * RPB) >> 10;            // batch
    int rowbase = blk * RPB;                // global row of r=0
    int j0L = i0L - 64;                     // union band start (local, signed)

    // ---------- Projection: q,k for OWN 8 rows (no redundancy) ----------
    // thread = (r:8, pq:2, uq:8, de:8); wave-uniform r,pq.
    {
        int de = t & 7, uq = (t >> 3) & 7, pq = (t >> 6) & 1, r = t >> 7;
        int row = rowbase + r;
        const float* W  = (pq ? Wx : Wt) + (size_t)(de * 32) * UU + uq * 4;
        const float* xr = x + (size_t)row * DD + de * 32;
        float a0 = 0.f, a1 = 0.f, a2 = 0.f, a3 = 0.f;
        #pragma unroll
        for (int dd = 0; dd < 32; dd += 4) {
            float4 xv = *(const float4*)(xr + dd);
            float4 w;
            w = *(const float4*)(W + (dd + 0) * UU);
            a0 = fmaf(xv.x, w.x, a0); a1 = fmaf(xv.x, w.y, a1);
            a2 = fmaf(xv.x, w.z, a2); a3 = fmaf(xv.x, w.w, a3);
            w = *(const float4*)(W + (dd + 1) * UU);
            a0 = fmaf(xv.y, w.x, a0); a1 = fmaf(xv.y, w.y, a1);
            a2 = fmaf(xv.y, w.z, a2); a3 = fmaf(xv.y, w.w, a3);
            w = *(const float4*)(W + (dd + 2) * UU);
            a0 = fmaf(xv.z, w.x, a0); a1 = fmaf(xv.z, w.y, a1);
            a2 = fmaf(xv.z, w.z, a2); a3 = fmaf(xv.z, w.w, a3);
            w = *(const float4*)(W + (dd + 3) * UU);
            a0 = fmaf(xv.w, w.x, a0); a1 = fmaf(xv.w, w.y, a1);
            a2 = fmaf(xv.w, w.z, a2); a3 = fmaf(xv.w, w.w, a3);
        }
        // reduce across de (8 adjacent lanes)
        #pragma unroll
        for (int off = 1; off < 8; off <<= 1) {
            a0 += __shfl_xor(a0, off);
            a1 += __shfl_xor(a1, off);
            a2 += __shfl_xor(a2, off);
            a3 += __shfl_xor(a3, off);
        }
        if (de == 0) {
            if (pq == 0) {
                float4 qv = make_float4(SCALE * a0, SCALE * a1, SCALE * a2, SCALE * a3);
                *(float4*)(qs + (size_t)row * UU + uq * 4) = qv;
            } else {
                const float4 bv = *(const float4*)(bh + uq * 4);
                kT[(size_t)(uq * 4 + 0) * NROW + row] = SCALE * (a0 + bv.x);
                kT[(size_t)(uq * 4 + 1) * NROW + row] = SCALE * (a1 + bv.y);
                kT[(size_t)(uq * 4 + 2) * NROW + row] = SCALE * (a2 + bv.z);
                kT[(size_t)(uq * 4 + 3) * NROW + row] = SCALE * (a3 + bv.w);
            }
        }
    }

    // zero s_a while waiting (block-local, safe pre-sync)
    for (int idx = t; idx < UNION * 9; idx += TPB) s_a[idx] = 0.0f;

    __threadfence();
    cg::this_grid().sync();

    // c0 = ba + sum(Wa)  (per-thread, L1-resident)
    float c0 = ba[0];
    #pragma unroll
    for (int u = 0; u < UU; u += 4) {
        float4 w4 = *(const float4*)(Wa + u);
        c0 += w4.x + w4.y + w4.z + w4.w;
    }

    // ---------- Phase 1: e[r][jr], one entry per thread, k from kT (global, coalesced) ----------
    {
        int r = t >> 7, jr = t & 127;
        int jru = r + jr;
        int jl = j0L + jru;                 // local j; band cond == jl in [0,LL)
        if ((unsigned)jl < (unsigned)LL) {
            const float* kp = kT + (size_t)(b * LL) + jl;   // + u*NROW per unit
            const float* qp = qs + (size_t)(rowbase + r) * UU;
            float acc = 0.0f;
            #pragma unroll
            for (int u = 0; u < UU; u += 4) {
                float4 q4 = *(const float4*)(qp + u);
                float4 w4 = *(const float4*)(Wa + u);
                float k0 = kp[(size_t)(u + 0) * NROW];
                float k1 = kp[(size_t)(u + 1) * NROW];
                float k2 = kp[(size_t)(u + 2) * NROW];
                float k3 = kp[(size_t)(u + 3) * NROW];
                acc = fmaf(w4.x, __builtin_amdgcn_rcpf(__builtin_amdgcn_exp2f(q4.x + k0) + 1.0f), acc);
                acc = fmaf(w4.y, __builtin_amdgcn_rcpf(__builtin_amdgcn_exp2f(q4.y + k1) + 1.0f), acc);
                acc = fmaf(w4.z, __builtin_amdgcn_rcpf(__builtin_amdgcn_exp2f(q4.z + k2) + 1.0f), acc);
                acc = fmaf(w4.w, __builtin_amdgcn_rcpf(__builtin_amdgcn_exp2f(q4.w + k3) + 1.0f), acc);
            }
            s_a[jru * 9 + r] = __expf(fmaf(-2.0f, acc, c0));
        }
    }
    __syncthreads();

    // ---------- Phase 3 (waves 0..3): j-outer PV, d-quad per thread, 8-row accs ----------
    // ---------- Phase 2 (waves 4..11): per-row denominators, concurrent ----------
    int w = t >> 6;
    if (w < GRP) {
        int g = w, lane = t & 63, d0 = lane * 4;
        float acc[RPB][4];
        #pragma unroll
        for (int r = 0; r < RPB; ++r) { acc[r][0]=0.f; acc[r][1]=0.f; acc[r][2]=0.f; acc[r][3]=0.f; }
        for (int jru = g; jru < UNION; jru += GRP) {
            int jl = j0L + jru;
            if ((unsigned)jl < (unsigned)LL) {
                float4 xv = *(const float4*)(x + (size_t)(b * LL + jl) * DD + d0);
                float4 e0 = *(const float4*)&s_a[jru * 9 + 0];   // aligned (144B row)
                float4 e1 = *(const float4*)&s_a[jru * 9 + 4];
                acc[0][0]=fmaf(e0.x,xv.x,acc[0][0]); acc[0][1]=fmaf(e0.x,xv.y,acc[0][1]); acc[0][2]=fmaf(e0.x,xv.z,acc[0][2]); acc[0][3]=fmaf(e0.x,xv.w,acc[0][3]);
                acc[1][0]=fmaf(e0.y,xv.x,acc[1][0]); acc[1][1]=fmaf(e0.y,xv.y,acc[1][1]); acc[1][2]=fmaf(e0.y,xv.z,acc[1][2]); acc[1][3]=fmaf(e0.y,xv.w,acc[1][3]);
                acc[2][0]=fmaf(e0.z,xv.x,acc[2][0]); acc[2][1]=fmaf(e0.z,xv.y,acc[2][1]); acc[2][2]=fmaf(e0.z,xv.z,acc[2][2]); acc[2][3]=fmaf(e0.z,xv.w,acc[2][3]);
                acc[3][0]=fmaf(e0.w,xv.x,acc[3][0]); acc[3][1]=fmaf(e0.w,xv.y,acc[3][1]); acc[3][2]=fmaf(e0.w,xv.z,acc[3][2]); acc[3][3]=fmaf(e0.w,xv.w,acc[3][3]);
                acc[4][0]=fmaf(e1.x,xv.x,acc[4][0]); acc[4][1]=fmaf(e1.x,xv.y,acc[4][1]); acc[4][2]=fmaf(e1.x,xv.z,acc[4][2]); acc[4][3]=fmaf(e1.x,xv.w,acc[4][3]);
                acc[5][0]=fmaf(e1.y,xv.x,acc[5][0]); acc[5][1]=fmaf(e1.y,xv.y,acc[5][1]); acc[5][2]=fmaf(e1.y,xv.z,acc[5][2]); acc[5][3]=fmaf(e1.y,xv.w,acc[5][3]);
                acc[6][0]=fmaf(e1.z,xv.x,acc[6][0]); acc[6][1]=fmaf(e1.z,xv.y,acc[6][1]); acc[6][2]=fmaf(e1.z,xv.z,acc[6][2]); acc[6][3]=fmaf(e1.z,xv.w,acc[6][3]);
                acc[7][0]=fmaf(e1.w,xv.x,acc[7][0]); acc[7][1]=fmaf(e1.w,xv.y,acc[7][1]); acc[7][2]=fmaf(e1.w,xv.z,acc[7][2]); acc[7][3]=fmaf(e1.w,xv.w,acc[7][3]);
            }
        }
        #pragma unroll
        for (int r = 0; r < RPB; ++r)
            *(float4*)&s_part[(g * RPB + r) * DD + d0] =
                make_float4(acc[r][0], acc[r][1], acc[r][2], acc[r][3]);
    } else if (w < 4 + RPB) {
        int r = w - 4, lane = t & 63;
        float v = s_a[lane * 9 + r] + s_a[(lane + 64) * 9 + r];
        if (lane < UNION - 128) v += s_a[(lane + 128) * 9 + r];
        #pragma unroll
        for (int off = 32; off > 0; off >>= 1) v += __shfl_xor(v, off);
        if (lane == 0) s_inv[r] = 1.0f / (v + 1e-7f);
    }
    __syncthreads();

    // ---------- Epilogue: reduce group partials, normalize, store float4 ----------
    if (t < (RPB * DD) / 4) {
        int r = t >> 6, d0 = (t & 63) * 4;
        float4 v = *(const float4*)&s_part[(0 * RPB + r) * DD + d0];
        #pragma unroll
        for (int g = 1; g < GRP; ++g) {
            float4 p = *(const float4*)&s_part[(g * RPB + r) * DD + d0];
            v.x += p.x; v.y += p.y; v.z += p.z; v.w += p.w;
        }
        float inv = s_inv[r];
        v.x *= inv; v.y *= inv; v.z *= inv; v.w *= inv;
        *(float4*)(out + (size_t)(rowbase + r) * DD + d0) = v;
    }
}

extern "C" void kernel_launch(void* const* d_in, const int* in_sizes, int n_in,
                              void* d_out, int out_size, void* d_ws, size_t ws_size,
                              hipStream_t stream) {
    const float* x  = (const float*)d_in[0];
    const float* Wt = (const float*)d_in[1];
    const float* Wx = (const float*)d_in[2];
    const float* bh = (const float*)d_in[3];
    const float* Wa = (const float*)d_in[4];
    const float* ba = (const float*)d_in[5];
    float* out = (float*)d_out;

    float* qs = (float*)d_ws;                     // [2048][32] prescaled q
    float* kT = qs + (size_t)NROW * UU;           // [32][2048] prescaled k (transposed)

    void* args[] = { (void*)&x, (void*)&Wt, (void*)&Wx, (void*)&bh,
                     (void*)&Wa, (void*)&ba, (void*)&out, (void*)&qs, (void*)&kT };
    hipLaunchCooperativeKernel((const void*)fused_kernel, dim3(NBLK), dim3(TPB),
                               args, 0, stream);
}

// Round 6
// 39.514 us; speedup vs baseline: 3.9857x; 3.9857x over previous
//
#include <hip/hip_runtime.h>
#include <math.h>

#define BB 2
#define LL 1024
#define DD 256
#define UU 32
#define RPB 4                   // rows per attn block
#define UNION (128 + RPB - 1)   // 131-row union band
#define TPB 1024
#define NROW (BB * LL)          // 2048
// prescale so tanh(v) = 1 - 2*rcp(exp2(SC*v)+1), SC = 2*log2(e)
#define SCALE 2.88539008177793f

// ---------------- Projection: q (prescaled) and kT (prescaled, transposed) ----------------
// thread = (de:8, uq:8, pq:2, r:2); 2 rows per 256-thread block, 1024 blocks.
__global__ __launch_bounds__(256, 8) void proj_kernel(
    const float* __restrict__ x, const float* __restrict__ Wt,
    const float* __restrict__ Wx, const float* __restrict__ bh,
    float* __restrict__ qs, float* __restrict__ kT)
{
    int t = threadIdx.x;
    int de = t & 7, uq = (t >> 3) & 7, pq = (t >> 6) & 1, r = t >> 7;
    int row = blockIdx.x * 2 + r;
    const float* W  = (pq ? Wx : Wt) + (size_t)(de * 32) * UU + uq * 4;
    const float* xr = x + (size_t)row * DD + de * 32;
    float a0 = 0.f, a1 = 0.f, a2 = 0.f, a3 = 0.f;
    #pragma unroll
    for (int dd = 0; dd < 32; dd += 4) {
        float4 xv = *(const float4*)(xr + dd);
        float4 w;
        w = *(const float4*)(W + (dd + 0) * UU);
        a0 = fmaf(xv.x, w.x, a0); a1 = fmaf(xv.x, w.y, a1);
        a2 = fmaf(xv.x, w.z, a2); a3 = fmaf(xv.x, w.w, a3);
        w = *(const float4*)(W + (dd + 1) * UU);
        a0 = fmaf(xv.y, w.x, a0); a1 = fmaf(xv.y, w.y, a1);
        a2 = fmaf(xv.y, w.z, a2); a3 = fmaf(xv.y, w.w, a3);
        w = *(const float4*)(W + (dd + 2) * UU);
        a0 = fmaf(xv.z, w.x, a0); a1 = fmaf(xv.z, w.y, a1);
        a2 = fmaf(xv.z, w.z, a2); a3 = fmaf(xv.z, w.w, a3);
        w = *(const float4*)(W + (dd + 3) * UU);
        a0 = fmaf(xv.w, w.x, a0); a1 = fmaf(xv.w, w.y, a1);
        a2 = fmaf(xv.w, w.z, a2); a3 = fmaf(xv.w, w.w, a3);
    }
    #pragma unroll
    for (int off = 1; off < 8; off <<= 1) {
        a0 += __shfl_xor(a0, off);
        a1 += __shfl_xor(a1, off);
        a2 += __shfl_xor(a2, off);
        a3 += __shfl_xor(a3, off);
    }
    if (de == 0) {
        if (pq == 0) {
            float4 qv = make_float4(SCALE * a0, SCALE * a1, SCALE * a2, SCALE * a3);
            *(float4*)(qs + (size_t)row * UU + uq * 4) = qv;
        } else {
            const float4 bv = *(const float4*)(bh + uq * 4);
            kT[(size_t)(uq * 4 + 0) * NROW + row] = SCALE * (a0 + bv.x);
            kT[(size_t)(uq * 4 + 1) * NROW + row] = SCALE * (a1 + bv.y);
            kT[(size_t)(uq * 4 + 2) * NROW + row] = SCALE * (a2 + bv.z);
            kT[(size_t)(uq * 4 + 3) * NROW + row] = SCALE * (a3 + bv.w);
        }
    }
}

// ---------------- Attention: 4 rows per 1024-thread block, 512 blocks (2/CU) ----------------
__global__ __launch_bounds__(TPB, 8) void attn_kernel(
    const float* __restrict__ x, const float* __restrict__ qs,
    const float* __restrict__ kT, const float* __restrict__ Wa,
    const float* __restrict__ ba, float* __restrict__ out)
{
    __shared__ float s_a4[(UNION + 1) * RPB];   // e-values, [jru][r], 16B rows
    __shared__ float s_part[4 * RPB * DD];      // phase-3 group partials (16 KB)
    __shared__ float s_inv[RPB];

    int t = threadIdx.x;
    int blk = blockIdx.x;
    int i0L = (blk * RPB) & (LL - 1);
    int b   = (blk * RPB) >> 10;
    int rowbase = blk * RPB;
    int j0L = i0L - 64;                          // union band start (local, signed)

    if (t < (UNION + 1) * RPB) s_a4[t] = 0.0f;
    __syncthreads();

    // c0 = ba + sum(Wa)
    float c0 = ba[0];
    #pragma unroll
    for (int u = 0; u < UU; u += 4) {
        float4 w4 = *(const float4*)(Wa + u);
        c0 += w4.x + w4.y + w4.z + w4.w;
    }

    // ---- Phase 1: 512 e-entries, 2 threads each (16 u per thread), k from kT (global) ----
    {
        int entry = t >> 1, half = t & 1;
        int r = entry >> 7, jr = entry & 127;
        int jru = r + jr;
        int jl = j0L + jru;                      // band condition == jl in [0,LL)
        float acc = 0.0f;
        if ((unsigned)jl < (unsigned)LL) {
            const float* kp = kT + (size_t)b * LL + jl + (size_t)(half * 16) * NROW;
            const float* qp = qs + (size_t)(rowbase + r) * UU + half * 16;
            const float* wp = Wa + half * 16;
            #pragma unroll
            for (int u = 0; u < 16; u += 4) {
                float4 q4 = *(const float4*)(qp + u);
                float4 w4 = *(const float4*)(wp + u);
                float k0 = kp[(size_t)(u + 0) * NROW];
                float k1 = kp[(size_t)(u + 1) * NROW];
                float k2 = kp[(size_t)(u + 2) * NROW];
                float k3 = kp[(size_t)(u + 3) * NROW];
                acc = fmaf(w4.x, __builtin_amdgcn_rcpf(__builtin_amdgcn_exp2f(q4.x + k0) + 1.0f), acc);
                acc = fmaf(w4.y, __builtin_amdgcn_rcpf(__builtin_amdgcn_exp2f(q4.y + k1) + 1.0f), acc);
                acc = fmaf(w4.z, __builtin_amdgcn_rcpf(__builtin_amdgcn_exp2f(q4.z + k2) + 1.0f), acc);
                acc = fmaf(w4.w, __builtin_amdgcn_rcpf(__builtin_amdgcn_exp2f(q4.w + k3) + 1.0f), acc);
            }
        }
        acc += __shfl_xor(acc, 1);               // pair shares same jl
        if (half == 0 && (unsigned)jl < (unsigned)LL)
            s_a4[jru * RPB + r] = __expf(fmaf(-2.0f, acc, c0));
    }
    __syncthreads();

    // ---- Phase 2 (waves 0-3): per-row denominators; runs before those waves' phase 3 ----
    if (t < 4 * 64) {
        int r = t >> 6, lane = t & 63;
        float v = s_a4[lane * RPB + r] + s_a4[(lane + 64) * RPB + r];
        if (lane < UNION + 1 - 128) v += s_a4[(lane + 128) * RPB + r];
        #pragma unroll
        for (int off = 32; off > 0; off >>= 1) v += __shfl_xor(v, off);
        if (lane == 0) s_inv[r] = 1.0f / (v + 1e-7f);
    }

    // ---- Phase 3: thread (g:4, d:256); one ds_read_b128 broadcast per step ----
    {
        int g = t >> 8, d = t & 255;
        float acc[RPB] = {0.f, 0.f, 0.f, 0.f};
        const float* xb = x + (size_t)b * LL * DD + d;
        for (int jru = g; jru < UNION; jru += 4) {
            int jl = j0L + jru;                  // wave-uniform guard
            if ((unsigned)jl < (unsigned)LL) {
                float xv = xb[(size_t)jl * DD];
                float4 e4 = *(const float4*)&s_a4[jru * RPB];
                acc[0] = fmaf(e4.x, xv, acc[0]);
                acc[1] = fmaf(e4.y, xv, acc[1]);
                acc[2] = fmaf(e4.z, xv, acc[2]);
                acc[3] = fmaf(e4.w, xv, acc[3]);
            }
        }
        #pragma unroll
        for (int r = 0; r < RPB; ++r)
            s_part[(g * RPB + r) * DD + d] = acc[r];
    }
    __syncthreads();

    // ---- Epilogue: reduce 4 group partials, normalize, store ----
    {
        int r = t >> 8, d = t & 255;
        float v = s_part[(0 * RPB + r) * DD + d]
                + s_part[(1 * RPB + r) * DD + d]
                + s_part[(2 * RPB + r) * DD + d]
                + s_part[(3 * RPB + r) * DD + d];
        out[(size_t)(rowbase + r) * DD + d] = v * s_inv[r];
    }
}

extern "C" void kernel_launch(void* const* d_in, const int* in_sizes, int n_in,
                              void* d_out, int out_size, void* d_ws, size_t ws_size,
                              hipStream_t stream) {
    const float* x  = (const float*)d_in[0];
    const float* Wt = (const float*)d_in[1];
    const float* Wx = (const float*)d_in[2];
    const float* bh = (const float*)d_in[3];
    const float* Wa = (const float*)d_in[4];
    const float* ba = (const float*)d_in[5];
    float* out = (float*)d_out;

    float* qs = (float*)d_ws;                     // [2048][32] prescaled q
    float* kT = qs + (size_t)NROW * UU;           // [32][2048] prescaled k (transposed)

    proj_kernel<<<NROW / 2, 256, 0, stream>>>(x, Wt, Wx, bh, qs, kT);
    attn_kernel<<<NROW / RPB, TPB, 0, stream>>>(x, qs, kT, Wa, ba, out);
}

// Round 7
// 36.034 us; speedup vs baseline: 4.3706x; 1.0966x over previous
//
#include <hip/hip_runtime.h>
#include <math.h>

#define BB 2
#define LL 1024
#define DD 256
#define UU 32
#define RPB 4                   // rows per attn block
#define UNION (128 + RPB - 1)   // 131-row union band
#define KROW 36                 // padded LDS k row (floats): b128-friendly, 2-way alias free
#define TPB 1024
#define NROW (BB * LL)          // 2048
// prescale so tanh(v) = 1 - 2*rcp(exp2(SC*v)+1), SC = 2*log2(e)
#define SCALE 2.88539008177793f

// ---------------- Projection: q and k, both prescaled, row-major; bias folded into k ----------------
// thread = (de:8, uq:8, pq:2, r:2); 2 rows per 256-thread block, 1024 blocks.
__global__ __launch_bounds__(256, 8) void proj_kernel(
    const float* __restrict__ x, const float* __restrict__ Wt,
    const float* __restrict__ Wx, const float* __restrict__ bh,
    float* __restrict__ qs, float* __restrict__ ks)
{
    int t = threadIdx.x;
    int de = t & 7, uq = (t >> 3) & 7, pq = (t >> 6) & 1, r = t >> 7;
    int row = blockIdx.x * 2 + r;
    const float* W  = (pq ? Wx : Wt) + (size_t)(de * 32) * UU + uq * 4;
    const float* xr = x + (size_t)row * DD + de * 32;
    float a0 = 0.f, a1 = 0.f, a2 = 0.f, a3 = 0.f;
    #pragma unroll
    for (int dd = 0; dd < 32; dd += 4) {
        float4 xv = *(const float4*)(xr + dd);
        float4 w;
        w = *(const float4*)(W + (dd + 0) * UU);
        a0 = fmaf(xv.x, w.x, a0); a1 = fmaf(xv.x, w.y, a1);
        a2 = fmaf(xv.x, w.z, a2); a3 = fmaf(xv.x, w.w, a3);
        w = *(const float4*)(W + (dd + 1) * UU);
        a0 = fmaf(xv.y, w.x, a0); a1 = fmaf(xv.y, w.y, a1);
        a2 = fmaf(xv.y, w.z, a2); a3 = fmaf(xv.y, w.w, a3);
        w = *(const float4*)(W + (dd + 2) * UU);
        a0 = fmaf(xv.z, w.x, a0); a1 = fmaf(xv.z, w.y, a1);
        a2 = fmaf(xv.z, w.z, a2); a3 = fmaf(xv.z, w.w, a3);
        w = *(const float4*)(W + (dd + 3) * UU);
        a0 = fmaf(xv.w, w.x, a0); a1 = fmaf(xv.w, w.y, a1);
        a2 = fmaf(xv.w, w.z, a2); a3 = fmaf(xv.w, w.w, a3);
    }
    #pragma unroll
    for (int off = 1; off < 8; off <<= 1) {
        a0 += __shfl_xor(a0, off);
        a1 += __shfl_xor(a1, off);
        a2 += __shfl_xor(a2, off);
        a3 += __shfl_xor(a3, off);
    }
    if (de == 0) {
        if (pq == 0) {
            *(float4*)(qs + (size_t)row * UU + uq * 4) =
                make_float4(SCALE * a0, SCALE * a1, SCALE * a2, SCALE * a3);
        } else {
            const float4 bv = *(const float4*)(bh + uq * 4);
            *(float4*)(ks + (size_t)row * UU + uq * 4) =
                make_float4(SCALE * (a0 + bv.x), SCALE * (a1 + bv.y),
                            SCALE * (a2 + bv.z), SCALE * (a3 + bv.w));
        }
    }
}

// ---------------- Attention: 4 rows per 1024-thread block, 512 blocks (2/CU, 32 waves) ----------------
__global__ __launch_bounds__(TPB, 8) void attn_kernel(
    const float* __restrict__ x, const float* __restrict__ qs,
    const float* __restrict__ ks, const float* __restrict__ Wa,
    const float* __restrict__ ba, float* __restrict__ out)
{
    __shared__ float s_k[UNION * KROW];         // prescaled k band (18.9 KB)
    __shared__ float s_a4[(UNION + 1) * RPB];   // e-values, [jru][r], 16B rows
    __shared__ float s_part[4 * RPB * DD];      // phase-3 group partials (16 KB)
    __shared__ float s_inv[RPB];

    int t = threadIdx.x;
    int blk = blockIdx.x;
    int i0L = (blk * RPB) & (LL - 1);
    int b   = (blk * RPB) >> 10;
    int rowbase = blk * RPB;
    int j0L = i0L - 64;                          // union band start (local, signed)

    // ---- stage k band: 131 rows x 8 float4 quads, b128 in / b128 out ----
    for (int idx = t; idx < UNION * 8; idx += TPB) {
        int jru = idx >> 3, uq = idx & 7;
        int jl = j0L + jru;
        if ((unsigned)jl < (unsigned)LL) {
            float4 kv = *(const float4*)(ks + (size_t)(b * LL + jl) * UU + uq * 4);
            *(float4*)&s_k[jru * KROW + uq * 4] = kv;
        }
    }
    if (t < (UNION + 1) * RPB) s_a4[t] = 0.0f;
    __syncthreads();

    // c0 = ba + sum(Wa)   (global broadcasts, L1)
    float c0 = ba[0];
    #pragma unroll
    for (int u = 0; u < UU; u += 4) {
        float4 w4 = *(const float4*)(Wa + u);
        c0 += w4.x + w4.y + w4.z + w4.w;
    }

    // ---- Phase 1: 512 e-entries, 2 threads each (16 u/thread); k via 4x ds_read_b128 ----
    {
        int entry = t >> 1, half = t & 1;
        int r = entry >> 7, jr = entry & 127;    // r is wave-uniform
        int jru = r + jr;
        int jl = j0L + jru;                      // band condition == jl in [0,LL)
        float acc = 0.0f;
        if ((unsigned)jl < (unsigned)LL) {
            const float* kp = &s_k[jru * KROW + half * 16];
            const float* qp = qs + (size_t)(rowbase + r) * UU + half * 16;
            const float* wp = Wa + half * 16;
            #pragma unroll
            for (int u = 0; u < 16; u += 4) {
                float4 k4 = *(const float4*)(kp + u);    // LDS b128
                float4 q4 = *(const float4*)(qp + u);    // global broadcast
                float4 w4 = *(const float4*)(wp + u);    // global broadcast
                acc = fmaf(w4.x, __builtin_amdgcn_rcpf(__builtin_amdgcn_exp2f(q4.x + k4.x) + 1.0f), acc);
                acc = fmaf(w4.y, __builtin_amdgcn_rcpf(__builtin_amdgcn_exp2f(q4.y + k4.y) + 1.0f), acc);
                acc = fmaf(w4.z, __builtin_amdgcn_rcpf(__builtin_amdgcn_exp2f(q4.z + k4.z) + 1.0f), acc);
                acc = fmaf(w4.w, __builtin_amdgcn_rcpf(__builtin_amdgcn_exp2f(q4.w + k4.w) + 1.0f), acc);
            }
        }
        acc += __shfl_xor(acc, 1);               // pair shares same jl
        if (half == 0 && (unsigned)jl < (unsigned)LL)
            s_a4[jru * RPB + r] = __expf(fmaf(-2.0f, acc, c0));
    }
    __syncthreads();

    // ---- Phase 2 (waves 0-3): per-row denominators ----
    if (t < 4 * 64) {
        int r = t >> 6, lane = t & 63;
        float v = s_a4[lane * RPB + r] + s_a4[(lane + 64) * RPB + r];
        if (lane < UNION + 1 - 128) v += s_a4[(lane + 128) * RPB + r];
        #pragma unroll
        for (int off = 32; off > 0; off >>= 1) v += __shfl_xor(v, off);
        if (lane == 0) s_inv[r] = 1.0f / (v + 1e-7f);
    }

    // ---- Phase 3: thread (g:4, d:256); one wave-uniform ds_read_b128 per step ----
    {
        int g = t >> 8, d = t & 255;
        float acc[RPB] = {0.f, 0.f, 0.f, 0.f};
        const float* xb = x + (size_t)b * LL * DD + d;
        for (int jru = g; jru < UNION; jru += 4) {
            int jl = j0L + jru;                  // wave-uniform guard
            if ((unsigned)jl < (unsigned)LL) {
                float xv = xb[(size_t)jl * DD];
                float4 e4 = *(const float4*)&s_a4[jru * RPB];
                acc[0] = fmaf(e4.x, xv, acc[0]);
                acc[1] = fmaf(e4.y, xv, acc[1]);
                acc[2] = fmaf(e4.z, xv, acc[2]);
                acc[3] = fmaf(e4.w, xv, acc[3]);
            }
        }
        #pragma unroll
        for (int r = 0; r < RPB; ++r)
            s_part[(g * RPB + r) * DD + d] = acc[r];
    }
    __syncthreads();

    // ---- Epilogue: reduce 4 group partials, normalize, store ----
    {
        int r = t >> 8, d = t & 255;
        float v = s_part[(0 * RPB + r) * DD + d]
                + s_part[(1 * RPB + r) * DD + d]
                + s_part[(2 * RPB + r) * DD + d]
                + s_part[(3 * RPB + r) * DD + d];
        out[(size_t)(rowbase + r) * DD + d] = v * s_inv[r];
    }
}

extern "C" void kernel_launch(void* const* d_in, const int* in_sizes, int n_in,
                              void* d_out, int out_size, void* d_ws, size_t ws_size,
                              hipStream_t stream) {
    const float* x  = (const float*)d_in[0];
    const float* Wt = (const float*)d_in[1];
    const float* Wx = (const float*)d_in[2];
    const float* bh = (const float*)d_in[3];
    const float* Wa = (const float*)d_in[4];
    const float* ba = (const float*)d_in[5];
    float* out = (float*)d_out;

    float* qs = (float*)d_ws;                     // [2048][32] prescaled q
    float* ks = qs + (size_t)NROW * UU;           // [2048][32] prescaled k (row-major)

    proj_kernel<<<NROW / 2, 256, 0, stream>>>(x, Wt, Wx, bh, qs, ks);
    attn_kernel<<<NROW / RPB, TPB, 0, stream>>>(x, qs, ks, Wa, ba, out);
}

// Round 8
// 25.290 us; speedup vs baseline: 6.2274x; 1.4248x over previous
//
#include <hip/hip_runtime.h>
#include <math.h>

#define BB 2
#define LL 1024
#define DD 256
#define UU 32
#define RPB 4                   // rows per attn block
#define UNION (128 + RPB - 1)   // 131-row union band
#define KROW 36                 // padded LDS k row: b128-aligned, 2-way bank alias (free)
#define TPB 1024
#define NROW (BB * LL)
// prescale so tanh(v) = 1 - 2*rcp(exp2(SC*v)+1), SC = 2*log2(e)
#define SCALE 2.88539008177793f

// ---------------- qk (R3 structure): 8 rows/block, 256 blocks ----------------
__global__ __launch_bounds__(256) void qk_kernel(
    const float* __restrict__ x, const float* __restrict__ Wt,
    const float* __restrict__ Wx, const float* __restrict__ bh,
    float* __restrict__ q, float* __restrict__ k)
{
    int tid = threadIdx.x;
    int u = tid & 31;
    int r = tid >> 5;
    int row = blockIdx.x * 8 + r;           // 0 .. B*L-1
    const float* xr = x + (size_t)row * DD;
    float accq = 0.0f;
    float acck = bh[u];
    #pragma unroll 4
    for (int d = 0; d < DD; ++d) {
        float xv = xr[d];
        accq = fmaf(xv, Wt[d * UU + u], accq);
        acck = fmaf(xv, Wx[d * UU + u], acck);
    }
    q[(size_t)row * UU + u] = SCALE * accq;
    k[(size_t)row * UU + u] = SCALE * acck;
}

// ---------------- attn: 4 rows per 1024-thread block, 512 blocks (32 waves/CU) ----------------
__global__ __launch_bounds__(TPB, 8) void attn_kernel(
    const float* __restrict__ x, const float* __restrict__ qs,
    const float* __restrict__ ks, const float* __restrict__ Wa,
    const float* __restrict__ ba, float* __restrict__ out)
{
    __shared__ float s_k[UNION * KROW];         // prescaled k band (18.9 KB)
    __shared__ float s_a4[(UNION + 1) * RPB];   // e-values, [jru][r], 16B rows
    __shared__ float s_q[RPB * UU];             // prescaled q
    __shared__ float s_wa[UU];
    __shared__ float s_c0;                      // ba + sum(Wa)
    __shared__ float s_inv[RPB];
    __shared__ float s_part[4 * RPB * DD];      // phase-3 group partials (16 KB)

    int t = threadIdx.x;
    int blk = blockIdx.x;
    int i0L = (blk * RPB) & (LL - 1);
    int b   = (blk * RPB) >> 10;
    int rowbase = blk * RPB;
    int j0L = i0L - 64;                          // union band start (local, signed)

    // ---- staging (all LDS-fed phase 1, as R3) ----
    if (t < RPB * UU) s_q[t] = qs[(size_t)rowbase * UU + t];
    if (t >= 128 && t < 128 + UU) s_wa[t - 128] = Wa[t - 128];
    if (t == 160) {
        float sw = ba[0];
        #pragma unroll
        for (int u = 0; u < UU; ++u) sw += Wa[u];
        s_c0 = sw;
    }
    if (t < (UNION + 1) * RPB) s_a4[t] = 0.0f;
    for (int idx = t; idx < UNION * 8; idx += TPB) {
        int jru = idx >> 3, uq = idx & 7;
        int jl = j0L + jru;
        if ((unsigned)jl < (unsigned)LL) {
            float4 kv = *(const float4*)(ks + (size_t)(b * LL + jl) * UU + uq * 4);
            *(float4*)&s_k[jru * KROW + uq * 4] = kv;
        }
    }
    __syncthreads();

    // ---- Phase 1: 512 e-entries, 2 threads each (16 u/thread), all-LDS operands ----
    {
        int entry = t >> 1, half = t & 1;
        int r = entry >> 7, jr = entry & 127;    // r wave-uniform
        int jru = r + jr;
        int jl = j0L + jru;                      // band condition == jl in [0,LL)
        float acc = 0.0f;
        if ((unsigned)jl < (unsigned)LL) {
            const float* kp = &s_k[jru * KROW + half * 16];
            const float* qp = &s_q[r * UU + half * 16];
            const float* wp = &s_wa[half * 16];
            #pragma unroll
            for (int u = 0; u < 16; u += 4) {
                float4 k4 = *(const float4*)(kp + u);    // ds_read_b128, 2-way alias
                float4 q4 = *(const float4*)(qp + u);    // LDS broadcast
                float4 w4 = *(const float4*)(wp + u);    // LDS broadcast
                acc = fmaf(w4.x, __builtin_amdgcn_rcpf(__builtin_amdgcn_exp2f(q4.x + k4.x) + 1.0f), acc);
                acc = fmaf(w4.y, __builtin_amdgcn_rcpf(__builtin_amdgcn_exp2f(q4.y + k4.y) + 1.0f), acc);
                acc = fmaf(w4.z, __builtin_amdgcn_rcpf(__builtin_amdgcn_exp2f(q4.z + k4.z) + 1.0f), acc);
                acc = fmaf(w4.w, __builtin_amdgcn_rcpf(__builtin_amdgcn_exp2f(q4.w + k4.w) + 1.0f), acc);
            }
        }
        acc += __shfl_xor(acc, 1);               // pair shares same jl
        if (half == 0 && (unsigned)jl < (unsigned)LL)
            s_a4[jru * RPB + r] = __expf(fmaf(-2.0f, acc, s_c0));
    }
    __syncthreads();

    // ---- Phase 2 (waves 0-3): per-row denominators; s_inv read only after next barrier ----
    if (t < 4 * 64) {
        int r = t >> 6, lane = t & 63;
        float v = s_a4[lane * RPB + r] + s_a4[(lane + 64) * RPB + r];
        if (lane < UNION + 1 - 128) v += s_a4[(lane + 128) * RPB + r];
        #pragma unroll
        for (int off = 32; off > 0; off >>= 1) v += __shfl_xor(v, off);
        if (lane == 0) s_inv[r] = 1.0f / (v + 1e-7f);
    }

    // ---- Phase 3: thread (g:4, d:256); one wave-uniform ds_read_b128 per step ----
    {
        int g = t >> 8, d = t & 255;
        float acc[RPB] = {0.f, 0.f, 0.f, 0.f};
        const float* xb = x + (size_t)b * LL * DD + d;
        for (int jru = g; jru < UNION; jru += 4) {
            int jl = j0L + jru;                  // wave-uniform guard
            if ((unsigned)jl < (unsigned)LL) {
                float xv = xb[(size_t)jl * DD];
                float4 e4 = *(const float4*)&s_a4[jru * RPB];
                acc[0] = fmaf(e4.x, xv, acc[0]);
                acc[1] = fmaf(e4.y, xv, acc[1]);
                acc[2] = fmaf(e4.z, xv, acc[2]);
                acc[3] = fmaf(e4.w, xv, acc[3]);
            }
        }
        #pragma unroll
        for (int r = 0; r < RPB; ++r)
            s_part[(g * RPB + r) * DD + d] = acc[r];
    }
    __syncthreads();

    // ---- Epilogue: reduce 4 group partials, normalize, store ----
    {
        int r = t >> 8, d = t & 255;
        float v = s_part[(0 * RPB + r) * DD + d]
                + s_part[(1 * RPB + r) * DD + d]
                + s_part[(2 * RPB + r) * DD + d]
                + s_part[(3 * RPB + r) * DD + d];
        out[(size_t)(rowbase + r) * DD + d] = v * s_inv[r];
    }
}

extern "C" void kernel_launch(void* const* d_in, const int* in_sizes, int n_in,
                              void* d_out, int out_size, void* d_ws, size_t ws_size,
                              hipStream_t stream) {
    const float* x  = (const float*)d_in[0];
    const float* Wt = (const float*)d_in[1];
    const float* Wx = (const float*)d_in[2];
    const float* bh = (const float*)d_in[3];
    const float* Wa = (const float*)d_in[4];
    const float* ba = (const float*)d_in[5];
    float* out = (float*)d_out;

    float* qs = (float*)d_ws;                     // [2048][32] prescaled q
    float* ks = qs + (size_t)NROW * UU;           // [2048][32] prescaled k (bias folded)

    qk_kernel<<<NROW / 8, 256, 0, stream>>>(x, Wt, Wx, bh, qs, ks);
    attn_kernel<<<NROW / RPB, TPB, 0, stream>>>(x, qs, ks, Wa, ba, out);
}

// Round 9
// 21.145 us; speedup vs baseline: 7.4482x; 1.1960x over previous
//
#include <hip/hip_runtime.h>
#include <math.h>

#define BB 2
#define LL 1024
#define DD 256
#define UU 32
#define RPB 4                   // rows per attn block
#define UNION (128 + RPB - 1)   // 131-row union band
#define KROW 36                 // padded LDS k row: b128-aligned, 2-way bank alias (free)
#define TPB 1024
#define NGRP 8                  // phase-3 jru groups
#define NROW (BB * LL)
// prescale so tanh(v) = 1 - 2*rcp(exp2(SC*v)+1), SC = 2*log2(e)
#define SCALE 2.88539008177793f

// ---------------- qk: 8 rows/block, d-range halved per lane pair (h), 256 blocks x 512 thr ----------------
__global__ __launch_bounds__(512) void qk_kernel(
    const float* __restrict__ x, const float* __restrict__ Wt,
    const float* __restrict__ Wx, const float* __restrict__ bh,
    float* __restrict__ q, float* __restrict__ k)
{
    int t = threadIdx.x;
    int u = t & 31, h = (t >> 5) & 1, r = t >> 6;   // wave = (u:32, h:2), r wave-uniform
    int row = blockIdx.x * 8 + r;
    const float* xr = x + (size_t)row * DD + h * 128;
    const float* wt = Wt + (size_t)(h * 128) * UU + u;
    const float* wx = Wx + (size_t)(h * 128) * UU + u;
    float accq = 0.0f, acck = 0.0f;
    #pragma unroll 4
    for (int d = 0; d < 128; ++d) {
        float xv = xr[d];
        accq = fmaf(xv, wt[(size_t)d * UU], accq);
        acck = fmaf(xv, wx[(size_t)d * UU], acck);
    }
    accq += __shfl_xor(accq, 32);                   // combine d-halves (h is lane bit 5)
    acck += __shfl_xor(acck, 32);
    if (h == 0) {
        q[(size_t)row * UU + u] = SCALE * accq;
        k[(size_t)row * UU + u] = SCALE * (acck + bh[u]);
    }
}

// ---------------- attn: 4 rows per 1024-thread block, 512 blocks (2/CU, 32 waves) ----------------
__global__ __launch_bounds__(TPB, 8) void attn_kernel(
    const float* __restrict__ x, const float* __restrict__ qs,
    const float* __restrict__ ks, const float* __restrict__ Wa,
    const float* __restrict__ ba, float* __restrict__ out)
{
    __shared__ float s_k[UNION * KROW];         // prescaled k band (18.9 KB)
    __shared__ float s_a4[(UNION + 1) * RPB];   // e-values, [jru][r], 16B rows
    __shared__ float s_q[RPB * UU];             // prescaled q
    __shared__ float s_wa[UU];
    __shared__ float s_c0;                      // ba + sum(Wa)
    __shared__ float s_inv[RPB];
    __shared__ float s_part[NGRP * RPB * DD];   // phase-3 group partials (32 KB)

    int t = threadIdx.x;
    int blk = blockIdx.x;
    int i0L = (blk * RPB) & (LL - 1);
    int b   = (blk * RPB) >> 10;
    int rowbase = blk * RPB;
    int j0L = i0L - 64;                          // union band start (local, signed)

    // ---- staging (all LDS-fed phase 1) ----
    if (t < RPB * UU) s_q[t] = qs[(size_t)rowbase * UU + t];
    if (t >= 128 && t < 128 + UU) s_wa[t - 128] = Wa[t - 128];
    if (t == 160) {
        float sw = ba[0];
        #pragma unroll
        for (int u = 0; u < UU; ++u) sw += Wa[u];
        s_c0 = sw;
    }
    if (t < (UNION + 1) * RPB) s_a4[t] = 0.0f;
    for (int idx = t; idx < UNION * 8; idx += TPB) {
        int jru = idx >> 3, uq = idx & 7;
        int jl = j0L + jru;
        if ((unsigned)jl < (unsigned)LL) {
            float4 kv = *(const float4*)(ks + (size_t)(b * LL + jl) * UU + uq * 4);
            *(float4*)&s_k[jru * KROW + uq * 4] = kv;
        }
    }
    __syncthreads();

    // ---- Phase 1: 512 e-entries, 2 threads each (16 u/thread), all-LDS operands ----
    {
        int entry = t >> 1, half = t & 1;
        int r = entry >> 7, jr = entry & 127;    // r wave-uniform
        int jru = r + jr;
        int jl = j0L + jru;                      // band condition == jl in [0,LL)
        float acc = 0.0f;
        if ((unsigned)jl < (unsigned)LL) {
            const float* kp = &s_k[jru * KROW + half * 16];
            const float* qp = &s_q[r * UU + half * 16];
            const float* wp = &s_wa[half * 16];
            #pragma unroll
            for (int u = 0; u < 16; u += 4) {
                float4 k4 = *(const float4*)(kp + u);    // ds_read_b128, 2-way alias
                float4 q4 = *(const float4*)(qp + u);    // LDS broadcast
                float4 w4 = *(const float4*)(wp + u);    // LDS broadcast
                acc = fmaf(w4.x, __builtin_amdgcn_rcpf(__builtin_amdgcn_exp2f(q4.x + k4.x) + 1.0f), acc);
                acc = fmaf(w4.y, __builtin_amdgcn_rcpf(__builtin_amdgcn_exp2f(q4.y + k4.y) + 1.0f), acc);
                acc = fmaf(w4.z, __builtin_amdgcn_rcpf(__builtin_amdgcn_exp2f(q4.z + k4.z) + 1.0f), acc);
                acc = fmaf(w4.w, __builtin_amdgcn_rcpf(__builtin_amdgcn_exp2f(q4.w + k4.w) + 1.0f), acc);
            }
        }
        acc += __shfl_xor(acc, 1);               // pair shares same jl
        if (half == 0 && (unsigned)jl < (unsigned)LL)
            s_a4[jru * RPB + r] = __expf(fmaf(-2.0f, acc, s_c0));
    }
    __syncthreads();

    // ---- Phase 2 (waves 0-3): per-row denominators; s_inv read only after next barrier ----
    if (t < 4 * 64) {
        int r = t >> 6, lane = t & 63;
        float v = s_a4[lane * RPB + r] + s_a4[(lane + 64) * RPB + r];
        if (lane < UNION + 1 - 128) v += s_a4[(lane + 128) * RPB + r];
        #pragma unroll
        for (int off = 32; off > 0; off >>= 1) v += __shfl_xor(v, off);
        if (lane == 0) s_inv[r] = 1.0f / (v + 1e-7f);
    }

    // ---- Phase 3: thread (g:8, rh:2, dq:64); float4 x loads, b64 uniform e-reads ----
    {
        int dq = t & 63, rh = (t >> 6) & 1, g = t >> 7;
        float a00 = 0.f, a01 = 0.f, a02 = 0.f, a03 = 0.f;
        float a10 = 0.f, a11 = 0.f, a12 = 0.f, a13 = 0.f;
        const float* xb = x + (size_t)b * LL * DD + dq * 4;
        for (int jru = g; jru < UNION; jru += NGRP) {
            int jl = j0L + jru;                  // wave-uniform guard
            if ((unsigned)jl < (unsigned)LL) {
                float4 xv = *(const float4*)(xb + (size_t)jl * DD);
                float2 e2 = *(const float2*)&s_a4[jru * RPB + rh * 2];
                a00 = fmaf(e2.x, xv.x, a00); a01 = fmaf(e2.x, xv.y, a01);
                a02 = fmaf(e2.x, xv.z, a02); a03 = fmaf(e2.x, xv.w, a03);
                a10 = fmaf(e2.y, xv.x, a10); a11 = fmaf(e2.y, xv.y, a11);
                a12 = fmaf(e2.y, xv.z, a12); a13 = fmaf(e2.y, xv.w, a13);
            }
        }
        *(float4*)&s_part[(g * RPB + rh * 2 + 0) * DD + dq * 4] = make_float4(a00, a01, a02, a03);
        *(float4*)&s_part[(g * RPB + rh * 2 + 1) * DD + dq * 4] = make_float4(a10, a11, a12, a13);
    }
    __syncthreads();

    // ---- Epilogue: reduce 8 group partials, normalize, store ----
    {
        int r = t >> 8, d = t & 255;
        float v = 0.0f;
        #pragma unroll
        for (int g = 0; g < NGRP; ++g)
            v += s_part[(g * RPB + r) * DD + d];
        out[(size_t)(rowbase + r) * DD + d] = v * s_inv[r];
    }
}

extern "C" void kernel_launch(void* const* d_in, const int* in_sizes, int n_in,
                              void* d_out, int out_size, void* d_ws, size_t ws_size,
                              hipStream_t stream) {
    const float* x  = (const float*)d_in[0];
    const float* Wt = (const float*)d_in[1];
    const float* Wx = (const float*)d_in[2];
    const float* bh = (const float*)d_in[3];
    const float* Wa = (const float*)d_in[4];
    const float* ba = (const float*)d_in[5];
    float* out = (float*)d_out;

    float* qs = (float*)d_ws;                     // [2048][32] prescaled q
    float* ks = qs + (size_t)NROW * UU;           // [2048][32] prescaled k (bias folded)

    qk_kernel<<<NROW / 8, 512, 0, stream>>>(x, Wt, Wx, bh, qs, ks);
    attn_kernel<<<NROW / RPB, TPB, 0, stream>>>(x, qs, ks, Wa, ba, out);
}